// Round 1
// baseline (525.779 us; speedup 1.0000x reference)
//
#include <hip/hip_runtime.h>
#include <stdint.h>

#define NF 8192          // features per row
#define NR 8192          // rows
#define TPB 256          // threads per block
#define RPB 8            // rows per block
#define TGRID (NR / RPB) // 1024 blocks
#define KSEL 2867        // floor(0.35 * 8192)
#define EQCAP 128

typedef float    floatx4 __attribute__((ext_vector_type(4)));
typedef uint32_t uintx4  __attribute__((ext_vector_type(4)));

// order-preserving float -> uint mapping (ascending)
__device__ __forceinline__ uint32_t f2s(float f) {
    uint32_t u = __float_as_uint(f);
    return u ^ ((uint32_t)((int32_t)u >> 31) | 0x80000000u);
}

__global__ __launch_bounds__(TPB) void boost_k(const float* __restrict__ dc,
                                               float* __restrict__ boost) {
    const int i = blockIdx.x * TPB + threadIdx.x;
    const float target = (float)KSEL / (float)NF; // 0.3499755859375, exact in f32
    boost[i] = expf(1.5f * (target - dc[i]));
}

__device__ __forceinline__ bool kept(uint32_t u, uint32_t T, uint32_t col,
                                     uint32_t keepall, uint32_t need,
                                     const uint32_t* eq) {
    if (u > T) return true;
    if (u != T) return false;
    if (keepall) return true;
    for (uint32_t i = 0; i < need; ++i)
        if (eq[i] == col) return true;
    return false;
}

__global__ __launch_bounds__(TPB, 4) void topk_k(const float* __restrict__ x,
                                                 const float* __restrict__ boost,
                                                 float* __restrict__ out,
                                                 uint32_t* __restrict__ partials) {
    // LDS: 32768 + 1024 + 512 + 512 + 32 ~= 34 KB -> 4 blocks/CU
    __shared__ __align__(16) uint32_t su[NF];
    __shared__ uint32_t hist[256];
    __shared__ uint32_t eq_i[EQCAP];
    __shared__ uint32_t eq_v[EQCAP];
    __shared__ uint32_t sh[8]; // 0: prefix/T, 1: kk/need, 3: raw eq count, 4: need, 5: keepall

    const int t = threadIdx.x;
    const int lane = t & 63;
    const int wv = t >> 6;

    // boost is identical for every row: hoist into registers once per block
    floatx4 bf[8];
    {
        const floatx4* b4 = (const floatx4*)boost;
#pragma unroll
        for (int j = 0; j < 8; ++j) bf[j] = b4[j * TPB + t];
    }

    uint32_t cnt[8] = {0, 0, 0, 0, 0, 0, 0, 0}; // packed per-column pos counts (4x u8)

    for (int r = 0; r < RPB; ++r) {
        const int row = blockIdx.x * RPB + r;
        const floatx4* x4 = (const floatx4*)(x + (size_t)row * NF);

        hist[t] = 0;
        if (t < 8) sh[t] = (t == 1) ? (uint32_t)KSEL : 0u;
        __syncthreads(); // also fences prev-row su readers vs new stores

        // stage: global -> regs -> LDS keys; build pass-1 histogram from registers
        floatx4 v[8];
#pragma unroll
        for (int j = 0; j < 8; ++j) {
            const int idx = j * TPB + t;
            floatx4 xv = __builtin_nontemporal_load(&x4[idx]);
            v[j] = xv;
            uintx4 u;
            u.x = f2s(xv.x * bf[j].x);
            u.y = f2s(xv.y * bf[j].y);
            u.z = f2s(xv.z * bf[j].z);
            u.w = f2s(xv.w * bf[j].w);
            ((uintx4*)su)[idx] = u;
            atomicAdd(&hist[u.x >> 24], 1u);
            atomicAdd(&hist[u.y >> 24], 1u);
            atomicAdd(&hist[u.z >> 24], 1u);
            atomicAdd(&hist[u.w >> 24], 1u);
        }
        __syncthreads();

        // 4-round radix select (8 bits per round, MSB first)
#pragma unroll
        for (int pass = 0; pass < 4; ++pass) {
            const int shift = 24 - 8 * pass;
            if (pass > 0) {
                const uint32_t prefix = sh[0];
                const uint32_t himask = 0xFFFFFFFFu << (shift + 8);
                hist[t] = 0;
                __syncthreads();
                if (pass < 3) {
#pragma unroll 4
                    for (int s = 0; s < 32; ++s) {
                        const uint32_t u = su[t + s * TPB];
                        if ((u & himask) == prefix)
                            atomicAdd(&hist[(u >> shift) & 0xFFu], 1u);
                    }
                } else {
                    // last pass: also collect candidate (idx,val) for tie handling
#pragma unroll 4
                    for (int s = 0; s < 32; ++s) {
                        const uint32_t u = su[t + s * TPB];
                        if ((u & himask) == prefix) {
                            atomicAdd(&hist[u & 0xFFu], 1u);
                            const uint32_t p = atomicAdd(&sh[3], 1u);
                            if (p < EQCAP) { eq_i[p] = (uint32_t)(t + s * TPB); eq_v[p] = u; }
                        }
                    }
                }
                __syncthreads();
            }
            // wave 0: suffix-scan the 256 bins, find bucket containing rank kk
            if (wv == 0) {
                const uintx4 h4 = ((const uintx4*)hist)[lane];
                const uint32_t g = h4.x + h4.y + h4.z + h4.w;
                uint32_t inc = g;
#pragma unroll
                for (int off = 1; off < 64; off <<= 1) {
                    const uint32_t o = __shfl_down(inc, off);
                    if (lane + off < 64) inc += o;
                }
                const uint32_t kk = sh[1];
                const uint32_t above = inc - g; // elements in strictly higher groups
                if (above < kk && kk <= inc) {
                    uint32_t c = above;
                    const uint32_t hh[4] = {h4.x, h4.y, h4.z, h4.w};
                    const uint32_t oldp = sh[0];
#pragma unroll
                    for (int b = 3; b >= 0; --b) {
                        c += hh[b];
                        if (c >= kk) {
                            sh[0] = oldp | ((uint32_t)(4 * lane + b) << shift);
                            sh[1] = kk - (c - hh[b]); // residual rank within bucket
                            break;
                        }
                    }
                }
            }
            __syncthreads();
        }
        // After last pass: sh[0] = exact k-th largest key T; sh[1] = #equal-to-T to keep.

        if (t == 0) {
            const uint32_t T = sh[0];
            const uint32_t need = sh[1];
            uint32_t nraw = sh[3];
            if (nraw > EQCAP) nraw = EQCAP;
            uint32_t m = 0;
            for (uint32_t i = 0; i < nraw; ++i)
                if (eq_v[i] == T) { const uint32_t ii = eq_i[i]; eq_i[m] = ii; ++m; }
            const uint32_t keepall = (m <= need) ? 1u : 0u;
            if (!keepall) { // keep lowest indices first (top_k stable tie-break)
                for (uint32_t i = 1; i < m; ++i) {
                    const uint32_t key = eq_i[i];
                    int jj = (int)i - 1;
                    while (jj >= 0 && eq_i[jj] > key) { eq_i[jj + 1] = eq_i[jj]; --jj; }
                    eq_i[jj + 1] = key;
                }
            }
            sh[4] = need;
            sh[5] = keepall;
        }
        __syncthreads();

        const uint32_t T = sh[0];
        const uint32_t need = sh[4];
        const uint32_t keepall = sh[5];
        floatx4* o4 = (floatx4*)(out + (size_t)row * NF);
#pragma unroll
        for (int j = 0; j < 8; ++j) {
            const int idx = j * TPB + t;
            const uintx4 u = ((const uintx4*)su)[idx];
            const floatx4 xv = v[j];
            floatx4 res;
            uint32_t add = 0;
            const bool k0 = kept(u.x, T, (uint32_t)(4 * idx + 0), keepall, need, eq_i);
            const bool k1 = kept(u.y, T, (uint32_t)(4 * idx + 1), keepall, need, eq_i);
            const bool k2 = kept(u.z, T, (uint32_t)(4 * idx + 2), keepall, need, eq_i);
            const bool k3 = kept(u.w, T, (uint32_t)(4 * idx + 3), keepall, need, eq_i);
            res.x = k0 ? xv.x : 0.0f;
            res.y = k1 ? xv.y : 0.0f;
            res.z = k2 ? xv.z : 0.0f;
            res.w = k3 ? xv.w : 0.0f;
            add += (k0 && xv.x > 0.0f) ? 1u : 0u;
            add += (k1 && xv.y > 0.0f) ? (1u << 8) : 0u;
            add += (k2 && xv.z > 0.0f) ? (1u << 16) : 0u;
            add += (k3 && xv.w > 0.0f) ? (1u << 24) : 0u;
            __builtin_nontemporal_store(res, &o4[idx]);
            cnt[j] += add; // per-byte max RPB=8, no overflow
        }
    }

    // packed per-block column counts -> workspace (coalesced, no atomics)
    {
        uint32_t* pb = partials + (size_t)blockIdx.x * (NF / 4);
#pragma unroll
        for (int j = 0; j < 8; ++j) pb[j * TPB + t] = cnt[j];
    }
}

// stage A: sum 16 packed partial words (byte max 16*8=128, no carry) — 512 blocks
__global__ __launch_bounds__(TPB) void redA_k(const uint32_t* __restrict__ partials,
                                              uint32_t* __restrict__ p2) {
    const int wg = blockIdx.x & 7;  // 8 word-groups of 256
    const int bg = blockIdx.x >> 3; // 64 slices of 16 blocks
    const int w = wg * TPB + threadIdx.x; // 0..2047
    uint32_t s = 0;
#pragma unroll
    for (int b = 0; b < 16; ++b)
        s += partials[(size_t)(bg * 16 + b) * (NF / 4) + w];
    p2[(size_t)bg * (NF / 4) + w] = s;
}

// stage B: unpack + finish EMA — 8 blocks
__global__ __launch_bounds__(TPB) void redB_k(const uint32_t* __restrict__ p2,
                                              const float* __restrict__ dc,
                                              float* __restrict__ dcout) {
    const int w = blockIdx.x * TPB + threadIdx.x; // 0..2047
    uint32_t s0 = 0, s1 = 0, s2 = 0, s3 = 0;
#pragma unroll 8
    for (int g = 0; g < 64; ++g) {
        const uint32_t p = p2[(size_t)g * (NF / 4) + w];
        s0 += p & 0xFFu;
        s1 += (p >> 8) & 0xFFu;
        s2 += (p >> 16) & 0xFFu;
        s3 += p >> 24;
    }
    const floatx4 d = ((const floatx4*)dc)[w];
    floatx4 rr;
    rr.x = 0.9f * d.x + 0.1f * (float)s0;
    rr.y = 0.9f * d.y + 0.1f * (float)s1;
    rr.z = 0.9f * d.z + 0.1f * (float)s2;
    rr.w = 0.9f * d.w + 0.1f * (float)s3;
    ((floatx4*)dcout)[w] = rr;
}

extern "C" void kernel_launch(void* const* d_in, const int* in_sizes, int n_in,
                              void* d_out, int out_size, void* d_ws, size_t ws_size,
                              hipStream_t stream) {
    (void)in_sizes; (void)n_in; (void)out_size; (void)ws_size;
    const float* x  = (const float*)d_in[0];
    const float* dc = (const float*)d_in[1];
    float* out   = (float*)d_out;
    float* dcout = out + (size_t)NR * NF;

    char* ws = (char*)d_ws;
    float*    boost    = (float*)ws;                       // 32 KB @ 0
    uint32_t* partials = (uint32_t*)(ws + (1u << 20));     // 8 MB  @ 1 MB
    uint32_t* p2       = (uint32_t*)(ws + (10u << 20));    // 512 KB @ 10 MB

    boost_k<<<dim3(NF / TPB), dim3(TPB), 0, stream>>>(dc, boost);
    topk_k<<<dim3(TGRID), dim3(TPB), 0, stream>>>(x, boost, out, partials);
    redA_k<<<dim3(512), dim3(TPB), 0, stream>>>(partials, p2);
    redB_k<<<dim3(8), dim3(TPB), 0, stream>>>(p2, dc, dcout);
}